// Round 6
// baseline (486.284 us; speedup 1.0000x reference)
//
#include <hip/hip_runtime.h>
#include <hip/hip_bf16.h>
#include <stdint.h>

#define B_DIM 8192
#define IN_DIMC 1024
#define HIDC 1024
#define K_DIM 1024
#define ODE_STEPS 6

typedef float f32x4 __attribute__((ext_vector_type(4)));
typedef short bf16x8 __attribute__((ext_vector_type(8)));
typedef unsigned short u16x8 __attribute__((ext_vector_type(8)));

__device__ __forceinline__ float bf2f(unsigned short u) {
    union { unsigned int u; float f; } c; c.u = ((unsigned int)u) << 16; return c.f;
}
__device__ __forceinline__ unsigned short f2bf(float f) {
    union { float f; unsigned int u; } c; c.f = f;
    unsigned int u = c.u;
    return (unsigned short)((u + 0x7fffu + ((u >> 16) & 1u)) >> 16);
}
__device__ __forceinline__ float fast_tanh(float x) {
    float e = __expf(2.0f * x);
    return 1.0f - 2.0f / (e + 1.0f);
}

// ---------------- convert all f32 inputs to bf16 in workspace ----------------
constexpr size_t XN    = (size_t)B_DIM * IN_DIMC;
constexpr size_t HN    = (size_t)B_DIM * HIDC;
constexpr size_t WINN  = (size_t)HIDC * IN_DIMC;
constexpr size_t WRECN = (size_t)HIDC * HIDC;
constexpr size_t WGN   = (size_t)HIDC * (IN_DIMC + HIDC);
constexpr size_t TOTQ  = (XN + HN + WINN + WRECN + WGN) / 4;

__global__ __launch_bounds__(256) void convert_all(
    const float* __restrict__ x, const float* __restrict__ h,
    const float* __restrict__ win, const float* __restrict__ wrec,
    const float* __restrict__ wgate,
    unsigned short* __restrict__ x_bf, unsigned short* __restrict__ h_bf,
    unsigned short* __restrict__ win_bf, unsigned short* __restrict__ wrec_bf,
    unsigned short* __restrict__ wgx_bf, unsigned short* __restrict__ wgh_bf)
{
    size_t q = (size_t)blockIdx.x * 256 + threadIdx.x;
    if (q >= TOTQ) return;
    size_t e = q * 4;
    const float* src; unsigned short* dst; size_t si, di;
    if (e < XN)                          { src = x;    si = e;                       dst = x_bf;    di = si; }
    else if (e < XN + HN)                { src = h;    si = e - XN;                  dst = h_bf;    di = si; }
    else if (e < XN + HN + WINN)         { src = win;  si = e - XN - HN;             dst = win_bf;  di = si; }
    else if (e < XN + HN + WINN + WRECN) { src = wrec; si = e - XN - HN - WINN;      dst = wrec_bf; di = si; }
    else {
        size_t i = e - XN - HN - WINN - WRECN;
        size_t row = i >> 11, col = i & 2047;
        src = wgate; si = i;
        if (col < 1024) { dst = wgx_bf; di = row * 1024 + col; }
        else            { dst = wgh_bf; di = row * 1024 + (col - 1024); }
    }
    float4 v = *(const float4*)(src + si);
    ushort4 o;
    o.x = f2bf(v.x); o.y = f2bf(v.y); o.z = f2bf(v.z); o.w = f2bf(v.w);
    *(ushort4*)(dst + di) = o;
}

// ---- fused dual-GEMM: R3 engine + ONE-TILE-DEEP FRAGMENT PIPELINE ----
// BM=256 BN=128 BK=32, 8 waves, 4 LDS buffers (128 KB), grid 256 = 1 blk/CU.
// Per tile t: STAGE(t+3) -> vmcnt(8) -> barrier -> read y(t) [buf t&3] +
// read af/x(t+1) [buf (t+1)&3, alternate frag set] -> lgkm(12) [af/x(t),
// issued LAST tile, already done] -> 16 MFMA acc1 -> lgkm(8) [y(t)] ->
// 16 MFMA acc2. Every wait references reads issued a full tile (~1500 cy)
// earlier: the 8-wave LDS read burst of tile t+1 drains UNDER tile t's MFMA
// cluster instead of serializing in front of it (the m201 mechanism).
// Gate proofs: vmcnt(8) before BAR(t) => stage(t+1) landed for ALL waves
// before any wave reads it; STAGE(t+3) overwrites buf (t-1)&3 whose reads
// were issued before BAR(t-1) (LDS FIFO order). lgkm(12): after afx(t) come
// y(t)4 + afx(t+1)8 = 12. lgkm(8): after y(t) come afx(t+1)8.
// LDS swizzle for 64B rows: 16B-slot ^= (row>>1)&3 (0 conflicts, R3-R5).
// Epilogue state layout unchanged from R3 (harness-verified):
// slot = ((bid*8 + wave)*16 + mi*4+ni)*64 + lane.
constexpr int BM = 256, BN = 128, BK = 32;
constexpr int NT = HIDC / BN;           // 8
constexpr int GRID = (B_DIM / BM) * NT; // 256
constexpr int NKT = K_DIM / BK;         // 32

__device__ __forceinline__ void gload_lds16(const void* g, void* l) {
    __builtin_amdgcn_global_load_lds(
        (const __attribute__((address_space(1))) void*)g,
        (__attribute__((address_space(3))) void*)l, 16, 0, 0);
}

#define MFMA_BF16 __builtin_amdgcn_mfma_f32_16x16x32_bf16

#define DS_READ(D, A_, O) \
    asm volatile("ds_read_b128 %0, %1 offset:" O : "=v"(D) : "v"(A_))

#define STAGE4(SQ, KE) do {                                                   \
    gload_lds16(sA  + (KE),          &SMEM[(SQ) * 8192 + dA]);                \
    gload_lds16(sA  + 16384 + (KE),  &SMEM[(SQ) * 8192 + dA + 512]);          \
    gload_lds16(sB1 + (KE),          &SMEM[32768 + (SQ) * 4096 + dB]);        \
    gload_lds16(sB2 + (KE),          &SMEM[49152 + (SQ) * 4096 + dB]);        \
} while (0)

// fragment reads: A from rdA + bufQ*16384 + mi*1024; B1 from rdB1 + bufQ*8192
// + ni*1024; B2 likewise. All offsets literal strings (proven path).
#define RD_AFX(FA, FX, a0,a1,a2,a3, b0,b1,b2,b3) do {                         \
    DS_READ(FA##_0, rdA,  a0); DS_READ(FA##_1, rdA,  a1);                     \
    DS_READ(FA##_2, rdA,  a2); DS_READ(FA##_3, rdA,  a3);                     \
    DS_READ(FX##_0, rdB1, b0); DS_READ(FX##_1, rdB1, b1);                     \
    DS_READ(FX##_2, rdB1, b2); DS_READ(FX##_3, rdB1, b3);                     \
} while (0)
#define RD_YQ(y0,y1,y2,y3) do {                                               \
    DS_READ(fy_0, rdB2, y0); DS_READ(fy_1, rdB2, y1);                         \
    DS_READ(fy_2, rdB2, y2); DS_READ(fy_3, rdB2, y3);                         \
} while (0)

#define RD_AFX_B0(FA, FX) RD_AFX(FA, FX, "0","1024","2048","3072",            "0","1024","2048","3072")
#define RD_AFX_B1(FA, FX) RD_AFX(FA, FX, "16384","17408","18432","19456",     "8192","9216","10240","11264")
#define RD_AFX_B2(FA, FX) RD_AFX(FA, FX, "32768","33792","34816","35840",     "16384","17408","18432","19456")
#define RD_AFX_B3(FA, FX) RD_AFX(FA, FX, "49152","50176","51200","52224",     "24576","25600","26624","27648")
#define RD_Y_B0() RD_YQ("0","1024","2048","3072")
#define RD_Y_B1() RD_YQ("8192","9216","10240","11264")
#define RD_Y_B2() RD_YQ("16384","17408","18432","19456")
#define RD_Y_B3() RD_YQ("24576","25600","26624","27648")

#define MFMA16(ACC, F0, F1, F2, F3, G0, G1, G2, G3) do {                      \
    ACC[0][0] = MFMA_BF16(F0, G0, ACC[0][0], 0, 0, 0);                        \
    ACC[1][0] = MFMA_BF16(F1, G0, ACC[1][0], 0, 0, 0);                        \
    ACC[2][0] = MFMA_BF16(F2, G0, ACC[2][0], 0, 0, 0);                        \
    ACC[3][0] = MFMA_BF16(F3, G0, ACC[3][0], 0, 0, 0);                        \
    ACC[0][1] = MFMA_BF16(F0, G1, ACC[0][1], 0, 0, 0);                        \
    ACC[1][1] = MFMA_BF16(F1, G1, ACC[1][1], 0, 0, 0);                        \
    ACC[2][1] = MFMA_BF16(F2, G1, ACC[2][1], 0, 0, 0);                        \
    ACC[3][1] = MFMA_BF16(F3, G1, ACC[3][1], 0, 0, 0);                        \
    ACC[0][2] = MFMA_BF16(F0, G2, ACC[0][2], 0, 0, 0);                        \
    ACC[1][2] = MFMA_BF16(F1, G2, ACC[1][2], 0, 0, 0);                        \
    ACC[2][2] = MFMA_BF16(F2, G2, ACC[2][2], 0, 0, 0);                        \
    ACC[3][2] = MFMA_BF16(F3, G2, ACC[3][2], 0, 0, 0);                        \
    ACC[0][3] = MFMA_BF16(F0, G3, ACC[0][3], 0, 0, 0);                        \
    ACC[1][3] = MFMA_BF16(F1, G3, ACC[1][3], 0, 0, 0);                        \
    ACC[2][3] = MFMA_BF16(F2, G3, ACC[2][3], 0, 0, 0);                        \
    ACC[3][3] = MFMA_BF16(F3, G3, ACC[3][3], 0, 0, 0);                        \
} while (0)

#define WAIT_SB(S) do { asm volatile("s_waitcnt " S ::: "memory");            \
                        __builtin_amdgcn_sched_barrier(0); } while (0)

// steady tile: PS=staging buf, KE=stage k-elems, VM=vmcnt, RDY=y-read macro
// (buf t&3), RDN=af/x-read macro (buf (t+1)&3), Fc/Xc = consume set (t&1),
// Fr/Xr = read-into set ((t+1)&1).
#define KITER6(PS, KE, VM, RDY, RDN, Fc, Xc, Fr, Xr) do {                     \
    STAGE4(PS, KE);                                                           \
    WAIT_SB("vmcnt(" VM ")");                                                 \
    asm volatile("s_barrier" ::: "memory");                                   \
    RDY();                                                                    \
    RDN(Fr, Xr);                                                              \
    WAIT_SB("lgkmcnt(12)");                                                   \
    __builtin_amdgcn_s_setprio(1);                                            \
    MFMA16(acc1, Fc##_0, Fc##_1, Fc##_2, Fc##_3, Xc##_0, Xc##_1, Xc##_2, Xc##_3); \
    WAIT_SB("lgkmcnt(8)");                                                    \
    MFMA16(acc2, Fc##_0, Fc##_1, Fc##_2, Fc##_3, fy_0, fy_1, fy_2, fy_3);     \
    __builtin_amdgcn_s_setprio(0);                                            \
} while (0)

#define KITER6_NS(VM, RDY, RDN, Fc, Xc, Fr, Xr) do {                          \
    WAIT_SB("vmcnt(" VM ")");                                                 \
    asm volatile("s_barrier" ::: "memory");                                   \
    RDY();                                                                    \
    RDN(Fr, Xr);                                                              \
    WAIT_SB("lgkmcnt(12)");                                                   \
    __builtin_amdgcn_s_setprio(1);                                            \
    MFMA16(acc1, Fc##_0, Fc##_1, Fc##_2, Fc##_3, Xc##_0, Xc##_1, Xc##_2, Xc##_3); \
    WAIT_SB("lgkmcnt(8)");                                                    \
    MFMA16(acc2, Fc##_0, Fc##_1, Fc##_2, Fc##_3, fy_0, fy_1, fy_2, fy_3);     \
    __builtin_amdgcn_s_setprio(0);                                            \
} while (0)

template<bool STEP>
__global__ __launch_bounds__(512, 2) void ltc_gemm(
    const unsigned short* __restrict__ A,
    const unsigned short* __restrict__ B1,
    const unsigned short* __restrict__ B2,
    const unsigned short* __restrict__ GXID,   // native layout, 8 bf16/slot
    const float* __restrict__ h_init,          // row-major f32 (step 0 only)
    float* __restrict__ h_nat,                 // native f32 state, in-place
    const float* __restrict__ log_tau,
    float* __restrict__ h_out,                 // final step: d_out half 0
    float* __restrict__ h_out2,                // final step: d_out half 1
    unsigned short* __restrict__ hbf_out,      // row-major bf16 (next A)
    const float* __restrict__ bias1, const float* __restrict__ bias2,
    unsigned short* __restrict__ GXID_out)     // pre-kernel output
{
    __shared__ __attribute__((aligned(16))) unsigned short SMEM[65536]; // 128 KB

    const int tid = threadIdx.x;
    const int w = tid >> 6, l = tid & 63;
    // bijective XCD swizzle (GRID % 8 == 0)
    const int bid = (blockIdx.x & 7) * (GRID / 8) + (blockIdx.x >> 3);
    const int mt = bid / NT, nt = bid % NT;
    const int m0 = mt * BM, n0 = nt * BN;
    const int wm = (w >> 1) * 64, wn = (w & 1) * 64;
    const int lm = l & 15, lq = l >> 4;

    // staging lanes: gload round = 16 rows x 4 slots of 16B; lane l -> row
    // l>>2, phys slot l&3, fetching global slot (l&3)^((row>>1)&3).
    const int lrg = l >> 2;
    const int gsl = (l & 3) ^ ((lrg >> 1) & 3);
    const unsigned short* sA  = A  + (size_t)(m0 + w * 32 + lrg) * K_DIM + gsl * 8;
    const unsigned short* sB1 = B1 + (size_t)(n0 + w * 16 + lrg) * K_DIM + gsl * 8;
    const unsigned short* sB2 = B2 + (size_t)(n0 + w * 16 + lrg) * K_DIM + gsl * 8;
    const int dA = w * 1024;   // elem off inside A buffer (wave stages 32 rows)
    const int dB = w * 512;    // elem off inside B buffers (wave stages 16 rows)

    // fragment read base byte addrs (swizzled): row = base16+lm, slot lq
    const int phys = lq ^ ((lm >> 1) & 3);
    const unsigned smem0 = (unsigned)(uintptr_t)&SMEM[0];
    const unsigned rdA  = smem0 +          (wm + lm) * 64 + phys * 16;
    const unsigned rdB1 = smem0 + 65536 + (wn + lm) * 64 + phys * 16;
    const unsigned rdB2 = smem0 + 98304 + (wn + lm) * 64 + phys * 16;

    f32x4 acc1[4][4], acc2[4][4];
    f32x4 z4 = {0.f, 0.f, 0.f, 0.f};
    #pragma unroll
    for (int i = 0; i < 4; i++)
        #pragma unroll
        for (int j = 0; j < 4; j++) { acc1[i][j] = z4; acc2[i][j] = z4; }

    // fragment sets (parity-double-buffered af/x, single y)
    bf16x8 fa0_0, fa0_1, fa0_2, fa0_3, fx0_0, fx0_1, fx0_2, fx0_3;
    bf16x8 fa1_0, fa1_1, fa1_2, fa1_3, fx1_0, fx1_1, fx1_2, fx1_3;
    bf16x8 fy_0, fy_1, fy_2, fy_3;

    // prologue: stage tiles 0,1,2 -> bufs 0,1,2; ensure stage(0) landed;
    // barrier; read af/x(0) into set 0 from buf 0.
    STAGE4(0, 0); STAGE4(1, 32); STAGE4(2, 64);
    WAIT_SB("vmcnt(8)");
    asm volatile("s_barrier" ::: "memory");
    RD_AFX_B0(fa0, fx0);

    #pragma unroll 1
    for (int tb = 0; tb < 28; tb += 4) {
        KITER6(3, (tb + 3) * 32, "8", RD_Y_B0, RD_AFX_B1, fa0, fx0, fa1, fx1); // t=tb+0
        KITER6(0, (tb + 4) * 32, "8", RD_Y_B1, RD_AFX_B2, fa1, fx1, fa0, fx0); // t=tb+1
        KITER6(1, (tb + 5) * 32, "8", RD_Y_B2, RD_AFX_B3, fa0, fx0, fa1, fx1); // t=tb+2
        KITER6(2, (tb + 6) * 32, "8", RD_Y_B3, RD_AFX_B0, fa1, fx1, fa0, fx0); // t=tb+3
    }
    KITER6(3, 31 * 32, "8", RD_Y_B0, RD_AFX_B1, fa0, fx0, fa1, fx1);           // t=28
    KITER6_NS("4", RD_Y_B1, RD_AFX_B2, fa1, fx1, fa0, fx0);                    // t=29
    KITER6_NS("0", RD_Y_B2, RD_AFX_B3, fa0, fx0, fa1, fx1);                    // t=30
    // t=31: buf 3; y only; MFMA on set 1 (read at t=30)
    RD_Y_B3();
    WAIT_SB("lgkmcnt(4)");
    __builtin_amdgcn_s_setprio(1);
    MFMA16(acc1, fa1_0, fa1_1, fa1_2, fa1_3, fx1_0, fx1_1, fx1_2, fx1_3);
    WAIT_SB("lgkmcnt(0)");
    MFMA16(acc2, fa1_0, fa1_1, fa1_2, fa1_3, fy_0, fy_1, fy_2, fy_3);
    __builtin_amdgcn_s_setprio(0);

    // epilogue: C/D layout col=lane&15, row=(lane>>4)*4+r  [m89-verified]
    constexpr float subdt = 1.0f / (float)ODE_STEPS;
    const size_t wslot = (((size_t)bid * 8 + w) * 16) * 64 + l;

    float pc1[4], pc2[4];   // per-ni hoisted: scale (STEP) or biases (!STEP)
    #pragma unroll
    for (int ni = 0; ni < 4; ni++) {
        const int gn = n0 + wn + ni * 16 + lm;
        if (STEP) {
            pc1[ni] = subdt * __expf(-log_tau[gn]);
        } else {
            pc1[ni] = bias1[gn];
            pc2[ni] = bias2[gn];
        }
    }

    #pragma unroll
    for (int mi = 0; mi < 4; mi++) {
        #pragma unroll
        for (int ni = 0; ni < 4; ni++) {
            const int gmb = m0 + wm + mi * 16 + lq * 4;
            const int gn  = n0 + wn + ni * 16 + lm;
            const size_t slot = wslot + (size_t)(mi * 4 + ni) * 64;
            if (STEP) {
                const float sc = pc1[ni];
                u16x8 gi = *(const u16x8*)&GXID[slot * 8];
                f32x4 st;
                if (h_init) {
                    #pragma unroll
                    for (int r = 0; r < 4; r++)
                        st[r] = h_init[(size_t)(gmb + r) * HIDC + gn];
                } else {
                    st = *(const f32x4*)&h_nat[slot * 4];
                }
                f32x4 hn;
                #pragma unroll
                for (int r = 0; r < 4; r++) {
                    float gx = bf2f((unsigned short)gi[r])     + acc1[mi][ni][r];
                    float dr = bf2f((unsigned short)gi[4 + r]) + acc2[mi][ni][r];
                    float gt = fast_tanh(dr) / (1.0f + __expf(-gx));
                    hn[r] = fmaf(sc, gt - st[r], st[r]);
                }
                if (h_out) {
                    #pragma unroll
                    for (int r = 0; r < 4; r++) {
                        size_t idx = (size_t)(gmb + r) * HIDC + gn;
                        h_out[idx]  = hn[r];
                        h_out2[idx] = hn[r];
                    }
                } else {
                    *(f32x4*)&h_nat[slot * 4] = hn;
                    #pragma unroll
                    for (int r = 0; r < 4; r++)
                        hbf_out[(size_t)(gmb + r) * HIDC + gn] = f2bf(hn[r]);
                }
            } else {
                u16x8 o;
                #pragma unroll
                for (int r = 0; r < 4; r++) {
                    o[r]     = f2bf(acc1[mi][ni][r] + pc1[ni]);
                    o[4 + r] = f2bf(acc2[mi][ni][r] + pc2[ni]);
                }
                *(u16x8*)&GXID_out[slot * 8] = o;
            }
        }
    }
}

extern "C" void kernel_launch(void* const* d_in, const int* in_sizes, int n_in,
                              void* d_out, int out_size, void* d_ws, size_t ws_size,
                              hipStream_t stream)
{
    const float* x    = (const float*)d_in[0];
    const float* h    = (const float*)d_in[1];
    const float* ltau = (const float*)d_in[2];
    const float* winw = (const float*)d_in[3];
    const float* winb = (const float*)d_in[4];
    const float* wrec = (const float*)d_in[5];
    const float* wg   = (const float*)d_in[6];
    const float* wgb  = (const float*)d_in[7];

    char* ws = (char*)d_ws;
    unsigned short* x_bf    = (unsigned short*)ws; ws += XN * 2;
    unsigned short* h_bf0   = (unsigned short*)ws; ws += HN * 2;
    unsigned short* h_bf1   = (unsigned short*)ws; ws += HN * 2;
    unsigned short* win_bf  = (unsigned short*)ws; ws += WINN * 2;
    unsigned short* wrec_bf = (unsigned short*)ws; ws += WRECN * 2;
    unsigned short* wgx_bf  = (unsigned short*)ws; ws += WINN * 2;
    unsigned short* wgh_bf  = (unsigned short*)ws; ws += WRECN * 2;
    unsigned short* GXID    = (unsigned short*)ws; ws += HN * 2 * 2;  // 32 MB
    float*          h_nat   = (float*)ws;          ws += HN * 4;      // 32 MB

    float* hout  = (float*)d_out;
    float* hout2 = hout + (size_t)B_DIM * HIDC;

    convert_all<<<(int)(TOTQ / 256), 256, 0, stream>>>(
        x, h, winw, wrec, wg, x_bf, h_bf0, win_bf, wrec_bf, wgx_bf, wgh_bf);

    // pre-loop: GXID = pack(x@Wgx^T + wgb, x@Win^T + winb) in native layout
    ltc_gemm<false><<<GRID, 512, 0, stream>>>(
        x_bf, wgx_bf, win_bf,
        nullptr, nullptr, nullptr, nullptr, nullptr, nullptr, nullptr,
        wgb, winb, GXID);

    unsigned short* hbf[2] = {h_bf0, h_bf1};
    for (int s = 0; s < ODE_STEPS; s++) {
        const bool last = (s == ODE_STEPS - 1);
        ltc_gemm<true><<<GRID, 512, 0, stream>>>(
            hbf[s & 1], wgh_bf, wrec_bf,
            GXID,
            (s == 0) ? h : nullptr,
            h_nat, ltau,
            last ? hout : nullptr, last ? hout2 : nullptr,
            last ? nullptr : hbf[(s + 1) & 1],
            nullptr, nullptr, nullptr);
    }
}